// Round 4
// baseline (383.310 us; speedup 1.0000x reference)
//
#include <hip/hip_runtime.h>
#include <math.h>

typedef unsigned int uint;
typedef unsigned short ushort;
typedef short short8 __attribute__((ext_vector_type(8)));
typedef float f32x4 __attribute__((ext_vector_type(4)));

#define B_ 2048
#define N_ 256
#define D_ 64
#define ND_ 16384
#define NN_ 65536
#define KIDX_ 52428u
#define SPLITK 16

// ---------------- ws layout (bytes) ----------------
#define WS_NODE   ((size_t)0)                      // node/final bf16 [B][N*D] : 64 MiB
#define WS_GPT    ((size_t)64*1024*1024)           // gpW1^T bf16 [e][k] : 2 MiB
#define WS_ADJF   (WS_GPT + (size_t)2*1024*1024)   // adj A-frag bf16 : 256 KiB slot
#define WS_W1T    (WS_ADJF + (size_t)256*1024)     // 2 MiB (dead after k_node)
#define WS_W2T    (WS_W1T + (size_t)2*1024*1024)   // 2 MiB (dead after k_node)
#define WS_GPARTS (WS_W1T)                         // overlay: f32 [16][2048][64] = 8 MiB
#define WS_SCAL   (WS_GPARTS + (size_t)8*1024*1024)

__device__ __forceinline__ ushort f2bf(float f) {
    uint u = __float_as_uint(f);
    u += 0x7fffu + ((u >> 16) & 1u);
    return (ushort)(u >> 16);
}
__device__ __forceinline__ float bf2f(ushort u) { return __uint_as_float(((uint)u) << 16); }

// exact float sigmoid via correctly-rounded double exp (matches numpy; verified R1-R3)
__device__ __forceinline__ float sigmoid_exact(float a) {
    float t = (float)exp(-(double)a);
    return 1.0f / (1.0f + t);
}

// ---------------- weight convert/transpose ----------------
__global__ __launch_bounds__(256) void k_convert(const float* __restrict__ W1,
                                                 const float* __restrict__ W2,
                                                 const float* __restrict__ gpW1,
                                                 ushort* __restrict__ W1t,
                                                 ushort* __restrict__ W2t,
                                                 ushort* __restrict__ gpt) {
    __shared__ ushort T[64][66];
    int bid = blockIdx.x, tid = threadIdx.x;
    const float* src;
    if (bid < 256) src = W1 + (size_t)bid * 4096;
    else if (bid < 512) src = W2 + (size_t)(bid - 256) * 4096;
    else src = gpW1 + (size_t)(bid - 512) * 64 * 64;
#pragma unroll
    for (int i = 0; i < 16; i++) {
        int idx = i * 256 + tid;
        int k = idx >> 6, e = idx & 63;
        T[e][k] = f2bf(src[idx]);
    }
    __syncthreads();
#pragma unroll
    for (int i = 0; i < 16; i++) {
        int idx = i * 256 + tid;
        int e = idx >> 6, k = idx & 63;
        ushort v = T[e][k];
        if (bid < 256) W1t[(size_t)bid * 4096 + idx] = v;
        else if (bid < 512) W2t[(size_t)(bid - 256) * 4096 + idx] = v;
        else gpt[(size_t)e * 16384 + (size_t)(bid - 512) * 64 + k] = v;
    }
}

// ---------------- exact rank select in PARAM space ----------------
__global__ __launch_bounds__(1024, 4) void k_radix_select(const float* __restrict__ adj_param,
                                                          uint* __restrict__ scal) {
    __shared__ uint histL[256 * 64];   // [bin][lane] : 64 KiB, 2 lanes/bank (free)
    __shared__ uint red[256];
    __shared__ uint bc[2];
    int tid = threadIdx.x;
    int lane = tid & 63;
    uint prefix = 0;
    uint rank = KIDX_;
    const uint4* pv = (const uint4*)adj_param;
#pragma unroll 1
    for (int pass = 0; pass < 4; pass++) {
        int shift = 24 - 8 * pass;
        for (int i = tid; i < 256 * 64; i += 1024) histL[i] = 0u;
        __syncthreads();
#pragma unroll 1
        for (int i = 0; i < 16; i++) {
            uint4 b4 = pv[i * 1024 + tid];
#pragma unroll
            for (int c = 0; c < 4; c++) {
                uint bits = (c == 0) ? b4.x : (c == 1) ? b4.y : (c == 2) ? b4.z : b4.w;
                uint key = bits ^ ((bits & 0x80000000u) ? 0xFFFFFFFFu : 0x80000000u);
                bool cand = (pass == 0) || ((key >> (32 - 8 * pass)) == prefix);
                if (cand) atomicAdd(&histL[(((key >> shift) & 0xffu) << 6) + lane], 1u);
            }
        }
        __syncthreads();
        if (tid < 256) {
            uint s = 0;
#pragma unroll
            for (int l = 0; l < 64; l++) s += histL[(tid << 6) + ((l + tid) & 63)];
            red[tid] = s;
        }
        __syncthreads();
        if (tid == 0) {
            uint c = 0;
            for (int b = 0; b < 256; b++) {
                uint h = red[b];
                if (c + h > rank) { bc[0] = (prefix << 8) | (uint)b; bc[1] = rank - c; break; }
                c += h;
            }
        }
        __syncthreads();
        prefix = bc[0];
        rank = bc[1];
        __syncthreads();
    }
    if (tid == 0) {
        uint key = prefix;
        uint bits = (key & 0x80000000u) ? (key ^ 0x80000000u) : ~key;
        scal[0] = __float_as_uint(sigmoid_exact(__uint_as_float(bits)));
    }
}

// ---------------- sigmoid + threshold + zero-diag; write adj fp32 + A-frag bf16 ---------
__global__ __launch_bounds__(256) void k_thresh(const float* __restrict__ adj_param,
                                                const uint* __restrict__ scal,
                                                float* __restrict__ adj_out,
                                                ushort* __restrict__ adjF) {
    int i = blockIdx.x * 256 + threadIdx.x;
    float thr = __uint_as_float(scal[0]);
    float s = sigmoid_exact(adj_param[i]);
    int r = i >> 8, c = i & 255;
    float v = (s > thr && r != c) ? s : 0.0f;
    adj_out[i] = v;
    uint chunk = ((((uint)(r >> 4) * 8u + (uint)(c >> 5)) * 4u + (uint)((c >> 3) & 3)) * 16u + (uint)(r & 15));
    adjF[chunk * 8u + (uint)(c & 7)] = f2bf(v);
}

// ---------------- stage 1: per-node 2-layer MLP ----------------
// Block = (node n, 256 batch rows in 4 rounds of 64). x staged via LDS with
// full-line loads; stores staged via per-wave LDS tile -> contiguous dwordx4.
__global__ __launch_bounds__(256, 4) void k_node(const float* __restrict__ x,
                                                 const ushort* __restrict__ W1t,
                                                 const ushort* __restrict__ W2t,
                                                 const float* __restrict__ b1,
                                                 const float* __restrict__ b2,
                                                 ushort* __restrict__ node) {
    __shared__ float Xs[64 * 68];        // x tile, row stride 68 floats (16B-aligned, uniform banks)
    __shared__ ushort Ws1[64][72];
    __shared__ ushort Ws2[64][72];
    __shared__ ushort St[4][16 * 72];    // per-wave C/h staging, row stride 72 ushorts
    int tid = threadIdx.x;
    int n = blockIdx.x, bt = blockIdx.y;

    const uint4* w1v = (const uint4*)(W1t + (size_t)n * 4096);
    const uint4* w2v = (const uint4*)(W2t + (size_t)n * 4096);
#pragma unroll
    for (int i = 0; i < 2; i++) {
        int idx = i * 256 + tid;
        int e = idx >> 3, k0 = (idx & 7) * 8;
        *(uint4*)&Ws1[e][k0] = w1v[idx];
        *(uint4*)&Ws2[e][k0] = w2v[idx];
    }
    // barrier for Ws folded into round-0 barrier below

    int wid = tid >> 6, lane = tid & 63, quad = lane >> 4, l16 = lane & 15;
    float bias1[4], bias2[4];
#pragma unroll
    for (int nt = 0; nt < 4; nt++) {
        bias1[nt] = b1[n * 64 + nt * 16 + l16];
        bias2[nt] = b2[n * 64 + nt * 16 + l16];
    }
    ushort* Sw = &St[wid][0];

#pragma unroll 1
    for (int rnd = 0; rnd < 4; rnd++) {
        int brow0 = bt * 256 + rnd * 64;
        // stage x tile 64 rows x 64 floats; per wave-instr: 4 rows x 256B (full lines)
#pragma unroll
        for (int i = 0; i < 4; i++) {
            int idx = i * 256 + tid;
            int rl = idx >> 4, seg = idx & 15;
            float4 v = *(const float4*)(x + (size_t)(brow0 + rl) * ND_ + n * 64 + seg * 4);
            *(float4*)&Xs[rl * 68 + seg * 4] = v;
        }
        __syncthreads();
        // A-frags from LDS
        short8 fa[2];
        int xr = (wid * 16 + l16) * 68;
#pragma unroll
        for (int ks = 0; ks < 2; ks++) {
            float4 A = *(const float4*)&Xs[xr + ks * 32 + quad * 8];
            float4 Bq = *(const float4*)&Xs[xr + ks * 32 + quad * 8 + 4];
            short8 a;
            a[0] = (short)f2bf(A.x); a[1] = (short)f2bf(A.y);
            a[2] = (short)f2bf(A.z); a[3] = (short)f2bf(A.w);
            a[4] = (short)f2bf(Bq.x); a[5] = (short)f2bf(Bq.y);
            a[6] = (short)f2bf(Bq.z); a[7] = (short)f2bf(Bq.w);
            fa[ks] = a;
        }
        __syncthreads();   // all frag reads done -> Xs reusable next round

        // layer 1
        f32x4 acc[4];
#pragma unroll
        for (int nt = 0; nt < 4; nt++) acc[nt] = (f32x4){0.f, 0.f, 0.f, 0.f};
#pragma unroll
        for (int ks = 0; ks < 2; ks++)
#pragma unroll
            for (int nt = 0; nt < 4; nt++) {
                short8 bf = *(const short8*)&Ws1[nt * 16 + l16][ks * 32 + quad * 8];
                acc[nt] = __builtin_amdgcn_mfma_f32_16x16x32_bf16(fa[ks], bf, acc[nt], 0, 0, 0);
            }
#pragma unroll
        for (int nt = 0; nt < 4; nt++)
#pragma unroll
            for (int r = 0; r < 4; r++) {
                float h = fmaxf(acc[nt][r] + bias1[nt], 0.0f);
                Sw[(quad * 4 + r) * 72 + nt * 16 + l16] = f2bf(h);
            }
        // layer 2 (per-wave LDS, DS ops in-order per wave)
        f32x4 acc2[4];
#pragma unroll
        for (int nt = 0; nt < 4; nt++) acc2[nt] = (f32x4){0.f, 0.f, 0.f, 0.f};
#pragma unroll
        for (int ks = 0; ks < 2; ks++) {
            short8 a2 = *(const short8*)&Sw[l16 * 72 + ks * 32 + quad * 8];
#pragma unroll
            for (int nt = 0; nt < 4; nt++) {
                short8 bf = *(const short8*)&Ws2[nt * 16 + l16][ks * 32 + quad * 8];
                acc2[nt] = __builtin_amdgcn_mfma_f32_16x16x32_bf16(a2, bf, acc2[nt], 0, 0, 0);
            }
        }
        // epilogue: stage bf16 C tile per-wave, then contiguous dwordx4 stores
#pragma unroll
        for (int nt = 0; nt < 4; nt++)
#pragma unroll
            for (int r = 0; r < 4; r++) {
                float v = acc2[nt][r] + bias2[nt];
                Sw[(quad * 4 + r) * 72 + nt * 16 + l16] = f2bf(v);
            }
#pragma unroll
        for (int half = 0; half < 2; half++) {
            int rloc = (lane >> 3) + half * 8;
            uint4 pk = *(const uint4*)&Sw[rloc * 72 + (lane & 7) * 8];
            *(uint4*)(node + (size_t)(brow0 + wid * 16 + rloc) * ND_ + n * 64 + (lane & 7) * 8) = pk;
        }
    }
}

// ---------------- stage 2: mixing GEMM per batch + residual ----------------
__global__ __launch_bounds__(256, 4) void k_mix(const ushort* __restrict__ adjF,
                                                ushort* __restrict__ node) {
    __shared__ ushort Bt[64 * 264];   // transposed staging, XOR-octet swizzle
    __shared__ ushort Cs[4][16 * 72]; // per-wave store staging
    int b = blockIdx.x, tid = threadIdx.x;
    int wid = tid >> 6, L = tid & 63, quad = L >> 4, l16 = L & 15;
    ushort* nb = node + (size_t)b * ND_;
    ushort* Cw = &Cs[wid][0];

#pragma unroll
    for (int t = 0; t < 8; t++) {
        int j = t * 32 + (tid >> 3);
        int d0 = (tid & 7) * 8;
        uint4 dw = *(const uint4*)(nb + j * 64 + d0);
        int jo = j >> 3, jl = j & 7;
        ushort vals[8];
        vals[0] = (ushort)(dw.x & 0xffffu); vals[1] = (ushort)(dw.x >> 16);
        vals[2] = (ushort)(dw.y & 0xffffu); vals[3] = (ushort)(dw.y >> 16);
        vals[4] = (ushort)(dw.z & 0xffffu); vals[5] = (ushort)(dw.z >> 16);
        vals[6] = (ushort)(dw.w & 0xffffu); vals[7] = (ushort)(dw.w >> 16);
#pragma unroll
        for (int c = 0; c < 8; c++) {
            Bt[(d0 + c) * 264 + ((jo ^ c) << 3) + jl] = vals[c];
        }
    }
    __syncthreads();

    f32x4 acc[4][4];
#pragma unroll
    for (int mt = 0; mt < 4; mt++)
#pragma unroll
        for (int nt = 0; nt < 4; nt++) acc[mt][nt] = (f32x4){0.f, 0.f, 0.f, 0.f};

#pragma unroll 2
    for (int ks = 0; ks < 8; ks++) {
        short8 af[4];
#pragma unroll
        for (int mt = 0; mt < 4; mt++) {
            int it = wid * 4 + mt;
            af[mt] = *(const short8*)&adjF[(size_t)((((it * 8 + ks) * 4 + quad) * 16 + l16)) * 8];
        }
        short8 bfr[4];
#pragma unroll
        for (int nt = 0; nt < 4; nt++) {
            int d = nt * 16 + l16;
            int o = (ks * 4 + quad) ^ (d & 7);
            bfr[nt] = *(const short8*)&Bt[d * 264 + (o << 3)];
        }
#pragma unroll
        for (int mt = 0; mt < 4; mt++)
#pragma unroll
            for (int nt = 0; nt < 4; nt++)
                acc[mt][nt] = __builtin_amdgcn_mfma_f32_16x16x32_bf16(af[mt], bfr[nt], acc[mt][nt], 0, 0, 0);
    }

#pragma unroll
    for (int mt = 0; mt < 4; mt++) {
        int it = wid * 4 + mt;
#pragma unroll
        for (int nt = 0; nt < 4; nt++) {
            int d = nt * 16 + l16;
#pragma unroll
            for (int r = 0; r < 4; r++) {
                int i = it * 16 + quad * 4 + r;
                int o = (i >> 3) ^ (d & 7);
                float nodev = bf2f(Bt[d * 264 + (o << 3) + (i & 7)]);
                float v = 0.5f * acc[mt][nt][r] + 0.5f * nodev;
                Cw[(quad * 4 + r) * 72 + d] = f2bf(v);
            }
        }
        // contiguous stores: per instr 8 rows x 128B = 1KB contiguous
#pragma unroll
        for (int half = 0; half < 2; half++) {
            int rloc = (L >> 3) + half * 8;
            uint4 pk = *(const uint4*)&Cw[rloc * 72 + (L & 7) * 8];
            *(uint4*)(nb + (size_t)(it * 16 + rloc) * 64 + (L & 7) * 8) = pk;
        }
    }
}

// ---------------- stage 3: global pool GEMM split-K=16 ----------------
__global__ __launch_bounds__(256) void k_gp1(const ushort* __restrict__ finalb,
                                             const ushort* __restrict__ gpt,
                                             float* __restrict__ gparts) {
    int bt = blockIdx.x, ksp = blockIdx.y, tid = threadIdx.x;
    int wid = tid >> 6, lane = tid & 63, quad = lane >> 4, l16 = lane & 15;
    size_t kc = (size_t)ksp * (16384 / SPLITK);
    int brow = bt * 64 + wid * 16 + l16;
    const ushort* arow = finalb + (size_t)brow * ND_ + kc;
    f32x4 acc[4];
#pragma unroll
    for (int nt = 0; nt < 4; nt++) acc[nt] = (f32x4){0.f, 0.f, 0.f, 0.f};
#pragma unroll 4
    for (int ks = 0; ks < (16384 / SPLITK) / 32; ks++) {
        short8 af = *(const short8*)(arow + ks * 32 + quad * 8);
#pragma unroll
        for (int nt = 0; nt < 4; nt++) {
            short8 bf = *(const short8*)(gpt + (size_t)(nt * 16 + l16) * ND_ + kc + ks * 32 + quad * 8);
            acc[nt] = __builtin_amdgcn_mfma_f32_16x16x32_bf16(af, bf, acc[nt], 0, 0, 0);
        }
    }
    float* gp = gparts + ((size_t)ksp * B_ + bt * 64) * 64;
#pragma unroll
    for (int nt = 0; nt < 4; nt++)
#pragma unroll
        for (int r = 0; r < 4; r++) {
            int b_loc = wid * 16 + quad * 4 + r;
            int e = nt * 16 + l16;
            gp[b_loc * 64 + e] = acc[nt][r];
        }
}

// ---------------- stage 4: reduce partials, bias+relu, gp2 (fp32) ----------------
__global__ __launch_bounds__(64) void k_gp2(const float* __restrict__ gparts,
                                            const float* __restrict__ gpb1,
                                            const float* __restrict__ gpW2,
                                            const float* __restrict__ gpb2,
                                            float* __restrict__ out) {
    __shared__ float gs[64];
    int b = blockIdx.x, e = threadIdx.x;
    float s = gpb1[e];
#pragma unroll
    for (int p = 0; p < SPLITK; p++) s += gparts[((size_t)p * B_ + b) * 64 + e];
    gs[e] = fmaxf(s, 0.0f);
    __syncthreads();
    if (e < 32) {
        float a = gpb2[e];
#pragma unroll 8
        for (int k2 = 0; k2 < 64; k2++) a += gs[k2] * gpW2[k2 * 32 + e];
        out[(size_t)b * 32 + e] = a;
    }
}

extern "C" void kernel_launch(void* const* d_in, const int* in_sizes, int n_in,
                              void* d_out, int out_size, void* d_ws, size_t ws_size,
                              hipStream_t stream) {
    const float* x = (const float*)d_in[0];
    const float* adj_param = (const float*)d_in[1];
    const float* W1 = (const float*)d_in[2];
    const float* b1 = (const float*)d_in[3];
    const float* W2 = (const float*)d_in[4];
    const float* b2 = (const float*)d_in[5];
    const float* gpW1 = (const float*)d_in[6];
    const float* gpb1 = (const float*)d_in[7];
    const float* gpW2 = (const float*)d_in[8];
    const float* gpb2 = (const float*)d_in[9];

    float* out = (float*)d_out;                 // [2048*32]
    float* adj_out = (float*)d_out + NN_;       // [256*256]

    char* ws = (char*)d_ws;
    ushort* node = (ushort*)(ws + WS_NODE);
    ushort* gpt = (ushort*)(ws + WS_GPT);
    ushort* adjF = (ushort*)(ws + WS_ADJF);
    ushort* W1t = (ushort*)(ws + WS_W1T);
    ushort* W2t = (ushort*)(ws + WS_W2T);
    float* gparts = (float*)(ws + WS_GPARTS);   // overlays W1t/W2t (dead after k_node)
    uint* scal = (uint*)(ws + WS_SCAL);

    k_convert<<<768, 256, 0, stream>>>(W1, W2, gpW1, W1t, W2t, gpt);
    k_radix_select<<<1, 1024, 0, stream>>>(adj_param, scal);
    k_thresh<<<256, 256, 0, stream>>>(adj_param, scal, adj_out, adjF);
    k_node<<<dim3(256, 8), 256, 0, stream>>>(x, W1t, W2t, b1, b2, node);
    k_mix<<<2048, 256, 0, stream>>>(adjF, node);
    k_gp1<<<dim3(32, SPLITK), 256, 0, stream>>>(node, gpt, gparts);
    k_gp2<<<2048, 64, 0, stream>>>(gparts, gpb1, gpW2, gpb2, out);
}

// Round 5
// 378.567 us; speedup vs baseline: 1.0125x; 1.0125x over previous
//
#include <hip/hip_runtime.h>
#include <math.h>

typedef unsigned int uint;
typedef unsigned short ushort;
typedef short short8 __attribute__((ext_vector_type(8)));
typedef float f32x4 __attribute__((ext_vector_type(4)));

#define B_ 2048
#define N_ 256
#define D_ 64
#define ND_ 16384
#define NN_ 65536
#define KIDX_ 52428u
#define SPLITK 16

// ---------------- ws layout (bytes) ----------------
#define WS_NODE   ((size_t)0)                      // node/final bf16 [B][N*D] : 64 MiB
#define WS_GPT    ((size_t)64*1024*1024)           // gpW1^T bf16 [e][k] : 2 MiB
#define WS_ADJF   (WS_GPT + (size_t)2*1024*1024)   // adj A-frag bf16 : 256 KiB slot
#define WS_W1T    (WS_ADJF + (size_t)256*1024)     // 2 MiB packed W1 frags (dead after k_node)
#define WS_W2T    (WS_W1T + (size_t)2*1024*1024)   // 2 MiB packed W2 frags (dead after k_node)
#define WS_GPARTS (WS_W1T)                         // overlay: f32 [16][2048][64] = 8 MiB
#define WS_SCAL   (WS_GPARTS + (size_t)8*1024*1024)

__device__ __forceinline__ ushort f2bf(float f) {
    uint u = __float_as_uint(f);
    u += 0x7fffu + ((u >> 16) & 1u);
    return (ushort)(u >> 16);
}
__device__ __forceinline__ float bf2f(ushort u) { return __uint_as_float(((uint)u) << 16); }

// exact float sigmoid via correctly-rounded double exp (matches numpy; verified R1-R4)
__device__ __forceinline__ float sigmoid_exact(float a) {
    float t = (float)exp(-(double)a);
    return 1.0f / (1.0f + t);
}

// B-fragment offset for 16x16x32 bf16: element (e=outcol, k) of a 64x64 W-slice.
// frag addr = (((nt*2+ks)*4+quad)*16+l16)*8 + pos ; nt=e>>4,l16=e&15, ks=k>>5,quad=(k>>3)&3,pos=k&7
__device__ __forceinline__ int wfrag_off(int e, int k) {
    return ((((e >> 4) * 2 + (k >> 5)) * 4 + ((k >> 3) & 3)) * 16 + (e & 15)) * 8 + (k & 7);
}

// ---------------- weight convert: pack W1/W2 in B-frag order; transpose gpW1 ----------------
__global__ __launch_bounds__(256) void k_convert(const float* __restrict__ W1,
                                                 const float* __restrict__ W2,
                                                 const float* __restrict__ gpW1,
                                                 ushort* __restrict__ W1f,
                                                 ushort* __restrict__ W2f,
                                                 ushort* __restrict__ gpt) {
    int bid = blockIdx.x, tid = threadIdx.x;
    if (bid < 512) {
        __shared__ ushort P[4096] __attribute__((aligned(16)));
        const float* src = (bid < 256) ? W1 + (size_t)bid * 4096 : W2 + (size_t)(bid - 256) * 4096;
#pragma unroll
        for (int i = 0; i < 16; i++) {
            int idx = i * 256 + tid;
            int k = idx >> 6, e = idx & 63;   // src is [k][e]
            P[wfrag_off(e, k)] = f2bf(src[idx]);
        }
        __syncthreads();
        ushort* dst = (bid < 256) ? W1f + (size_t)bid * 4096 : W2f + (size_t)(bid - 256) * 4096;
#pragma unroll
        for (int i = 0; i < 2; i++)
            ((uint4*)dst)[i * 256 + tid] = ((const uint4*)P)[i * 256 + tid];
    } else {
        __shared__ ushort T[64][66];
        const float* src = gpW1 + (size_t)(bid - 512) * 64 * 64;
#pragma unroll
        for (int i = 0; i < 16; i++) {
            int idx = i * 256 + tid;
            int k = idx >> 6, e = idx & 63;
            T[e][k] = f2bf(src[idx]);
        }
        __syncthreads();
#pragma unroll
        for (int i = 0; i < 16; i++) {
            int idx = i * 256 + tid;
            int e = idx >> 6, k = idx & 63;
            gpt[(size_t)e * 16384 + (size_t)(bid - 512) * 64 + k] = T[e][k];
        }
    }
}

// ---------------- exact rank select in PARAM space ----------------
__global__ __launch_bounds__(1024, 4) void k_radix_select(const float* __restrict__ adj_param,
                                                          uint* __restrict__ scal) {
    __shared__ uint histL[256 * 64];   // [bin][lane] : 64 KiB, 2 lanes/bank (free)
    __shared__ uint red[256];
    __shared__ uint bc[2];
    int tid = threadIdx.x;
    int lane = tid & 63;
    uint prefix = 0;
    uint rank = KIDX_;
    const uint4* pv = (const uint4*)adj_param;
#pragma unroll 1
    for (int pass = 0; pass < 4; pass++) {
        int shift = 24 - 8 * pass;
        for (int i = tid; i < 256 * 64; i += 1024) histL[i] = 0u;
        __syncthreads();
#pragma unroll 1
        for (int i = 0; i < 16; i++) {
            uint4 b4 = pv[i * 1024 + tid];
#pragma unroll
            for (int c = 0; c < 4; c++) {
                uint bits = (c == 0) ? b4.x : (c == 1) ? b4.y : (c == 2) ? b4.z : b4.w;
                uint key = bits ^ ((bits & 0x80000000u) ? 0xFFFFFFFFu : 0x80000000u);
                bool cand = (pass == 0) || ((key >> (32 - 8 * pass)) == prefix);
                if (cand) atomicAdd(&histL[(((key >> shift) & 0xffu) << 6) + lane], 1u);
            }
        }
        __syncthreads();
        if (tid < 256) {
            uint s = 0;
#pragma unroll
            for (int l = 0; l < 64; l++) s += histL[(tid << 6) + ((l + tid) & 63)];
            red[tid] = s;
        }
        __syncthreads();
        if (tid == 0) {
            uint c = 0;
            for (int b = 0; b < 256; b++) {
                uint h = red[b];
                if (c + h > rank) { bc[0] = (prefix << 8) | (uint)b; bc[1] = rank - c; break; }
                c += h;
            }
        }
        __syncthreads();
        prefix = bc[0];
        rank = bc[1];
        __syncthreads();
    }
    if (tid == 0) {
        uint key = prefix;
        uint bits = (key & 0x80000000u) ? (key ^ 0x80000000u) : ~key;
        scal[0] = __float_as_uint(sigmoid_exact(__uint_as_float(bits)));
    }
}

// ---------------- sigmoid + threshold + zero-diag; write adj fp32 + A-frag bf16 ---------
__global__ __launch_bounds__(256) void k_thresh(const float* __restrict__ adj_param,
                                                const uint* __restrict__ scal,
                                                float* __restrict__ adj_out,
                                                ushort* __restrict__ adjF) {
    int i = blockIdx.x * 256 + threadIdx.x;
    float thr = __uint_as_float(scal[0]);
    float s = sigmoid_exact(adj_param[i]);
    int r = i >> 8, c = i & 255;
    float v = (s > thr && r != c) ? s : 0.0f;
    adj_out[i] = v;
    uint chunk = ((((uint)(r >> 4) * 8u + (uint)(c >> 5)) * 4u + (uint)((c >> 3) & 3)) * 16u + (uint)(r & 15));
    adjF[chunk * 8u + (uint)(c & 7)] = f2bf(v);
}

// ---------------- stage 1: per-node 2-layer MLP, barrier-free per-wave streaming -------
// Block = (node n, 128 batch rows). ONE barrier (weights); each wave owns private
// Xs/St regions and free-runs 2 rounds of 16 rows: stage(full-line)->frag->MFMA->store.
__global__ __launch_bounds__(256, 3) void k_node(const float* __restrict__ x,
                                                 const ushort* __restrict__ W1f,
                                                 const ushort* __restrict__ W2f,
                                                 const float* __restrict__ b1,
                                                 const float* __restrict__ b2,
                                                 ushort* __restrict__ node) {
    __shared__ ushort Wf1[4096] __attribute__((aligned(16)));   // B-frag packed, conflict-free
    __shared__ ushort Wf2[4096] __attribute__((aligned(16)));
    __shared__ float Xs[4][16 * 68];     // per-wave x tile (stride 68 floats)
    __shared__ ushort St[4][16 * 72];    // per-wave h/C staging (stride 72 ushorts)
    int tid = threadIdx.x;
    int n = blockIdx.x, bt = blockIdx.y;

    const uint4* w1v = (const uint4*)(W1f + (size_t)n * 4096);
    const uint4* w2v = (const uint4*)(W2f + (size_t)n * 4096);
#pragma unroll
    for (int i = 0; i < 2; i++) {
        ((uint4*)Wf1)[i * 256 + tid] = w1v[i * 256 + tid];
        ((uint4*)Wf2)[i * 256 + tid] = w2v[i * 256 + tid];
    }

    int wid = tid >> 6, lane = tid & 63, quad = lane >> 4, l16 = lane & 15;
    float bias1[4], bias2[4];
#pragma unroll
    for (int nt = 0; nt < 4; nt++) {
        bias1[nt] = b1[n * 64 + nt * 16 + l16];
        bias2[nt] = b2[n * 64 + nt * 16 + l16];
    }
    __syncthreads();   // the ONLY barrier: Wf1/Wf2 visible

    float* Xw = &Xs[wid][0];
    ushort* Sw = &St[wid][0];

#pragma unroll
    for (int rnd = 0; rnd < 2; rnd++) {
        int rbase = bt * 128 + (wid * 2 + rnd) * 16;
        // stage 16 rows x 256B, full-line loads: per instr 4 rows x 256B contiguous
#pragma unroll
        for (int i = 0; i < 4; i++) {
            int idx = i * 64 + lane;
            int rl = idx >> 4, seg = idx & 15;
            *(float4*)&Xw[rl * 68 + seg * 4] =
                *(const float4*)(x + (size_t)(rbase + rl) * ND_ + n * 64 + seg * 4);
        }
        // A-frags from own region (per-wave DS in-order; no barrier)
        short8 fa[2];
        int xr = l16 * 68;
#pragma unroll
        for (int ks = 0; ks < 2; ks++) {
            float4 A = *(const float4*)&Xw[xr + ks * 32 + quad * 8];
            float4 Bq = *(const float4*)&Xw[xr + ks * 32 + quad * 8 + 4];
            short8 a;
            a[0] = (short)f2bf(A.x); a[1] = (short)f2bf(A.y);
            a[2] = (short)f2bf(A.z); a[3] = (short)f2bf(A.w);
            a[4] = (short)f2bf(Bq.x); a[5] = (short)f2bf(Bq.y);
            a[6] = (short)f2bf(Bq.z); a[7] = (short)f2bf(Bq.w);
            fa[ks] = a;
        }
        // layer 1
        f32x4 acc[4];
#pragma unroll
        for (int nt = 0; nt < 4; nt++) acc[nt] = (f32x4){0.f, 0.f, 0.f, 0.f};
#pragma unroll
        for (int ks = 0; ks < 2; ks++)
#pragma unroll
            for (int nt = 0; nt < 4; nt++) {
                short8 bf = *(const short8*)&Wf1[(((nt * 2 + ks) * 4 + quad) * 16 + l16) * 8];
                acc[nt] = __builtin_amdgcn_mfma_f32_16x16x32_bf16(fa[ks], bf, acc[nt], 0, 0, 0);
            }
#pragma unroll
        for (int nt = 0; nt < 4; nt++)
#pragma unroll
            for (int r = 0; r < 4; r++) {
                float h = fmaxf(acc[nt][r] + bias1[nt], 0.0f);
                Sw[(quad * 4 + r) * 72 + nt * 16 + l16] = f2bf(h);
            }
        // layer 2
        f32x4 acc2[4];
#pragma unroll
        for (int nt = 0; nt < 4; nt++) acc2[nt] = (f32x4){0.f, 0.f, 0.f, 0.f};
#pragma unroll
        for (int ks = 0; ks < 2; ks++) {
            short8 a2 = *(const short8*)&Sw[l16 * 72 + ks * 32 + quad * 8];
#pragma unroll
            for (int nt = 0; nt < 4; nt++) {
                short8 bf = *(const short8*)&Wf2[(((nt * 2 + ks) * 4 + quad) * 16 + l16) * 8];
                acc2[nt] = __builtin_amdgcn_mfma_f32_16x16x32_bf16(a2, bf, acc2[nt], 0, 0, 0);
            }
        }
        // epilogue: stage bf16 tile, then contiguous dwordx4 stores (8 rows x 128B/instr)
#pragma unroll
        for (int nt = 0; nt < 4; nt++)
#pragma unroll
            for (int r = 0; r < 4; r++) {
                float v = acc2[nt][r] + bias2[nt];
                Sw[(quad * 4 + r) * 72 + nt * 16 + l16] = f2bf(v);
            }
#pragma unroll
        for (int half = 0; half < 2; half++) {
            int rloc = (lane >> 3) + half * 8;
            uint4 pk = *(const uint4*)&Sw[rloc * 72 + (lane & 7) * 8];
            *(uint4*)(node + (size_t)(rbase + rloc) * ND_ + n * 64 + (lane & 7) * 8) = pk;
        }
    }
}

// ---------------- stage 2: mixing GEMM per batch + residual ----------------
__global__ __launch_bounds__(256, 3) void k_mix(const ushort* __restrict__ adjF,
                                                ushort* __restrict__ node) {
    __shared__ ushort Bt[64 * 264];   // transposed staging, XOR-octet swizzle
    __shared__ ushort Cs[4][16 * 72]; // per-wave store staging
    int b = blockIdx.x, tid = threadIdx.x;
    int wid = tid >> 6, L = tid & 63, quad = L >> 4, l16 = L & 15;
    ushort* nb = node + (size_t)b * ND_;
    ushort* Cw = &Cs[wid][0];

#pragma unroll
    for (int t = 0; t < 8; t++) {
        int j = t * 32 + (tid >> 3);
        int d0 = (tid & 7) * 8;
        uint4 dw = *(const uint4*)(nb + j * 64 + d0);
        int jo = j >> 3, jl = j & 7;
        ushort vals[8];
        vals[0] = (ushort)(dw.x & 0xffffu); vals[1] = (ushort)(dw.x >> 16);
        vals[2] = (ushort)(dw.y & 0xffffu); vals[3] = (ushort)(dw.y >> 16);
        vals[4] = (ushort)(dw.z & 0xffffu); vals[5] = (ushort)(dw.z >> 16);
        vals[6] = (ushort)(dw.w & 0xffffu); vals[7] = (ushort)(dw.w >> 16);
#pragma unroll
        for (int c = 0; c < 8; c++) {
            Bt[(d0 + c) * 264 + ((jo ^ c) << 3) + jl] = vals[c];
        }
    }
    __syncthreads();

    f32x4 acc[4][4];
#pragma unroll
    for (int mt = 0; mt < 4; mt++)
#pragma unroll
        for (int nt = 0; nt < 4; nt++) acc[mt][nt] = (f32x4){0.f, 0.f, 0.f, 0.f};

#pragma unroll 2
    for (int ks = 0; ks < 8; ks++) {
        short8 af[4];
#pragma unroll
        for (int mt = 0; mt < 4; mt++) {
            int it = wid * 4 + mt;
            af[mt] = *(const short8*)&adjF[(size_t)((((it * 8 + ks) * 4 + quad) * 16 + l16)) * 8];
        }
        short8 bfr[4];
#pragma unroll
        for (int nt = 0; nt < 4; nt++) {
            int d = nt * 16 + l16;
            int o = (ks * 4 + quad) ^ (d & 7);
            bfr[nt] = *(const short8*)&Bt[d * 264 + (o << 3)];
        }
#pragma unroll
        for (int mt = 0; mt < 4; mt++)
#pragma unroll
            for (int nt = 0; nt < 4; nt++)
                acc[mt][nt] = __builtin_amdgcn_mfma_f32_16x16x32_bf16(af[mt], bfr[nt], acc[mt][nt], 0, 0, 0);
    }

#pragma unroll
    for (int mt = 0; mt < 4; mt++) {
        int it = wid * 4 + mt;
#pragma unroll
        for (int nt = 0; nt < 4; nt++) {
            int d = nt * 16 + l16;
#pragma unroll
            for (int r = 0; r < 4; r++) {
                int i = it * 16 + quad * 4 + r;
                int o = (i >> 3) ^ (d & 7);
                float nodev = bf2f(Bt[d * 264 + (o << 3) + (i & 7)]);
                float v = 0.5f * acc[mt][nt][r] + 0.5f * nodev;
                Cw[(quad * 4 + r) * 72 + d] = f2bf(v);
            }
        }
#pragma unroll
        for (int half = 0; half < 2; half++) {
            int rloc = (L >> 3) + half * 8;
            uint4 pk = *(const uint4*)&Cw[rloc * 72 + (L & 7) * 8];
            *(uint4*)(nb + (size_t)(it * 16 + rloc) * 64 + (L & 7) * 8) = pk;
        }
    }
}

// ---------------- stage 3: global pool GEMM split-K=16 ----------------
__global__ __launch_bounds__(256) void k_gp1(const ushort* __restrict__ finalb,
                                             const ushort* __restrict__ gpt,
                                             float* __restrict__ gparts) {
    int bt = blockIdx.x, ksp = blockIdx.y, tid = threadIdx.x;
    int wid = tid >> 6, lane = tid & 63, quad = lane >> 4, l16 = lane & 15;
    size_t kc = (size_t)ksp * (16384 / SPLITK);
    int brow = bt * 64 + wid * 16 + l16;
    const ushort* arow = finalb + (size_t)brow * ND_ + kc;
    f32x4 acc[4];
#pragma unroll
    for (int nt = 0; nt < 4; nt++) acc[nt] = (f32x4){0.f, 0.f, 0.f, 0.f};
#pragma unroll 4
    for (int ks = 0; ks < (16384 / SPLITK) / 32; ks++) {
        short8 af = *(const short8*)(arow + ks * 32 + quad * 8);
#pragma unroll
        for (int nt = 0; nt < 4; nt++) {
            short8 bf = *(const short8*)(gpt + (size_t)(nt * 16 + l16) * ND_ + kc + ks * 32 + quad * 8);
            acc[nt] = __builtin_amdgcn_mfma_f32_16x16x32_bf16(af, bf, acc[nt], 0, 0, 0);
        }
    }
    float* gp = gparts + ((size_t)ksp * B_ + bt * 64) * 64;
#pragma unroll
    for (int nt = 0; nt < 4; nt++)
#pragma unroll
        for (int r = 0; r < 4; r++) {
            int b_loc = wid * 16 + quad * 4 + r;
            int e = nt * 16 + l16;
            gp[b_loc * 64 + e] = acc[nt][r];
        }
}

// ---------------- stage 4: reduce partials, bias+relu, gp2 (fp32) ----------------
__global__ __launch_bounds__(64) void k_gp2(const float* __restrict__ gparts,
                                            const float* __restrict__ gpb1,
                                            const float* __restrict__ gpW2,
                                            const float* __restrict__ gpb2,
                                            float* __restrict__ out) {
    __shared__ float gs[64];
    int b = blockIdx.x, e = threadIdx.x;
    float s = gpb1[e];
#pragma unroll
    for (int p = 0; p < SPLITK; p++) s += gparts[((size_t)p * B_ + b) * 64 + e];
    gs[e] = fmaxf(s, 0.0f);
    __syncthreads();
    if (e < 32) {
        float a = gpb2[e];
#pragma unroll 8
        for (int k2 = 0; k2 < 64; k2++) a += gs[k2] * gpW2[k2 * 32 + e];
        out[(size_t)b * 32 + e] = a;
    }
}

extern "C" void kernel_launch(void* const* d_in, const int* in_sizes, int n_in,
                              void* d_out, int out_size, void* d_ws, size_t ws_size,
                              hipStream_t stream) {
    const float* x = (const float*)d_in[0];
    const float* adj_param = (const float*)d_in[1];
    const float* W1 = (const float*)d_in[2];
    const float* b1 = (const float*)d_in[3];
    const float* W2 = (const float*)d_in[4];
    const float* b2 = (const float*)d_in[5];
    const float* gpW1 = (const float*)d_in[6];
    const float* gpb1 = (const float*)d_in[7];
    const float* gpW2 = (const float*)d_in[8];
    const float* gpb2 = (const float*)d_in[9];

    float* out = (float*)d_out;                 // [2048*32]
    float* adj_out = (float*)d_out + NN_;       // [256*256]

    char* ws = (char*)d_ws;
    ushort* node = (ushort*)(ws + WS_NODE);
    ushort* gpt = (ushort*)(ws + WS_GPT);
    ushort* adjF = (ushort*)(ws + WS_ADJF);
    ushort* W1f = (ushort*)(ws + WS_W1T);
    ushort* W2f = (ushort*)(ws + WS_W2T);
    float* gparts = (float*)(ws + WS_GPARTS);   // overlays W1f/W2f (dead after k_node)
    uint* scal = (uint*)(ws + WS_SCAL);

    k_convert<<<768, 256, 0, stream>>>(W1, W2, gpW1, W1f, W2f, gpt);
    k_radix_select<<<1, 1024, 0, stream>>>(adj_param, scal);
    k_thresh<<<256, 256, 0, stream>>>(adj_param, scal, adj_out, adjF);
    k_node<<<dim3(256, 16), 256, 0, stream>>>(x, W1f, W2f, b1, b2, node);
    k_mix<<<2048, 256, 0, stream>>>(adjF, node);
    k_gp1<<<dim3(32, SPLITK), 256, 0, stream>>>(node, gpt, gparts);
    k_gp2<<<2048, 64, 0, stream>>>(gparts, gpb1, gpW2, gpb2, out);
}